// Round 4
// baseline (963.422 us; speedup 1.0000x reference)
//
#include <hip/hip_runtime.h>
#include <hip/hip_bf16.h>
#include <math.h>

#define N_NODES   100000
#define N_EDGES   1600000
#define D_FEAT    128
#define N_CLASSES 64

#define BKT_SHIFT 7                     // 128 nodes per bucket
#define BKT_NODES 128
#define NB        782                   // ceil(100000/128)
#define CAP       2560                  // per-bucket capacity (avg 2048, 11 sigma headroom)
#define CHUNK     8192                  // edges per bin block
#define NBLK_A    ((N_EDGES + CHUNK - 1) / CHUNK)   // 196

// Tightly packed ws layout (total 34,012,160 B — under the R2-proven ws_size):
//   deg    @ 0          (400,000 B)
//   bcnt   @ 400,384    (3,128 B)
//   binned @ 404,480    (8,007,680 B)
//   zp     @ 8,412,160  (25,600,000 B)
#define OFF_BCNT   400384
#define OFF_BINNED 404480
#define OFF_ZP     8412160

// ---------------------------------------------------------------------------
// K1: deg[i] = 1 (self-loop); bcnt[b] = 0
// ---------------------------------------------------------------------------
__global__ __launch_bounds__(256) void init_kernel(int* __restrict__ deg,
                                                   int* __restrict__ bcnt) {
    int i = blockIdx.x * 256 + threadIdx.x;
    if (i < N_NODES) deg[i] = 1;
    if (i < NB) bcnt[i] = 0;
}

// ---------------------------------------------------------------------------
// K2: deg[dst[e]] += 1  (in-degree histogram)
// ---------------------------------------------------------------------------
__global__ __launch_bounds__(256) void count_deg_kernel(const int* __restrict__ dst,
                                                        int* __restrict__ deg) {
    int e = blockIdx.x * 256 + threadIdx.x;
    if (e < N_EDGES) atomicAdd(&deg[dst[e]], 1);
}

// ---------------------------------------------------------------------------
// K3: zp[i][c] = rsqrt(deg[i]) * sum_k x[i][k]*W[c][k]
// ---------------------------------------------------------------------------
__global__ __launch_bounds__(256) void gemm_kernel(const float* __restrict__ x,
                                                   const float* __restrict__ W,
                                                   const int* __restrict__ deg,
                                                   float* __restrict__ zp) {
    __shared__ float Ws[N_CLASSES * 132];
    __shared__ float Xs[32 * D_FEAT];
    const int tid = threadIdx.x;

    for (int i = tid; i < N_CLASSES * D_FEAT; i += 256)
        Ws[(i >> 7) * 132 + (i & 127)] = W[i];

    const float4* __restrict__ x4 = (const float4*)(x + (size_t)blockIdx.x * 32 * D_FEAT);
    float4* Xs4 = (float4*)Xs;
    for (int i = tid; i < 32 * (D_FEAT / 4); i += 256)
        Xs4[i] = x4[i];
    __syncthreads();

    const int c  = tid & 63;
    const int w  = tid >> 6;
    const int rb = w * 8;
    float acc[8] = {0.f, 0.f, 0.f, 0.f, 0.f, 0.f, 0.f, 0.f};

#pragma unroll 4
    for (int k4 = 0; k4 < D_FEAT / 4; k4++) {
        float4 wv = *(const float4*)&Ws[c * 132 + k4 * 4];
#pragma unroll
        for (int r = 0; r < 8; r++) {
            float4 xv = *(const float4*)&Xs[(rb + r) * D_FEAT + k4 * 4];
            acc[r] += xv.x * wv.x;
            acc[r] += xv.y * wv.y;
            acc[r] += xv.z * wv.z;
            acc[r] += xv.w * wv.w;
        }
    }

    const int row0 = blockIdx.x * 32 + rb;
#pragma unroll
    for (int r = 0; r < 8; r++) {
        int row = row0 + r;
        float dinv = rsqrtf((float)deg[row]);
        zp[row * N_CLASSES + c] = acc[r] * dinv;
    }
}

// ---------------------------------------------------------------------------
// K4: bin edges into NB coarse buckets (128 nodes each).
//     Per block: LDS histogram -> one global atomic per touched bucket
//     reserves a contiguous run -> scatter (src<<7)|(dst&127) into the run.
//     Run writes are block-local contiguous spans => no cross-XCD
//     partial-line write amplification. CAP clamp = pure memory guard.
// ---------------------------------------------------------------------------
__global__ __launch_bounds__(256) void bin_kernel(const int* __restrict__ src,
                                                  const int* __restrict__ dst,
                                                  int* __restrict__ bcnt,
                                                  int* __restrict__ binned) {
    __shared__ int hist[NB];
    __shared__ int rbase[NB];
    const int tid = threadIdx.x;
    const int e0 = blockIdx.x * CHUNK;
    const int e1 = min(e0 + CHUNK, N_EDGES);

    for (int i = tid; i < NB; i += 256) hist[i] = 0;
    __syncthreads();

    for (int e = e0 + tid; e < e1; e += 256)
        atomicAdd(&hist[dst[e] >> BKT_SHIFT], 1);
    __syncthreads();

    for (int i = tid; i < NB; i += 256) {
        int h = hist[i];
        if (h) rbase[i] = atomicAdd(&bcnt[i], h);
        hist[i] = 0;                       // reuse as within-run cursor
    }
    __syncthreads();

    for (int e = e0 + tid; e < e1; e += 256) {
        int d = dst[e];
        int bkt = d >> BKT_SHIFT;
        int pos = atomicAdd(&hist[bkt], 1);
        int off = rbase[bkt] + pos;
        if (off < CAP)                     // memory guard (never taken in practice)
            binned[bkt * CAP + off] = (src[e] << BKT_SHIFT) | (d & (BKT_NODES - 1));
    }
}

// ---------------------------------------------------------------------------
// K5: per-bucket aggregation + fused bias/log-softmax.
//     One block per bucket; 32KB LDS fp32 accumulator [128 nodes x 64 cls].
// ---------------------------------------------------------------------------
__global__ __launch_bounds__(512) void agg_kernel(const int* __restrict__ deg,
                                                  const int* __restrict__ bcnt,
                                                  const int* __restrict__ binned,
                                                  const float* __restrict__ zp,
                                                  const float* __restrict__ b,
                                                  float* __restrict__ out) {
    __shared__ float acc[BKT_NODES * N_CLASSES];   // 32 KB
    const int tid  = threadIdx.x;
    const int lane = tid & 63;
    const int wid  = tid >> 6;                     // 0..7

    for (int i = tid; i < BKT_NODES * N_CLASSES; i += 512) acc[i] = 0.f;
    __syncthreads();

    const int n    = min(bcnt[blockIdx.x], CAP);
    const int base = blockIdx.x * CAP;

    for (int eb = wid * 64; eb < n; eb += 512) {
        const int cnt = min(n - eb, 64);
        int v = (lane < cnt) ? binned[base + eb + lane] : 0;
        int j = 0;
        for (; j + 4 <= cnt; j += 4) {
            int s0 = __shfl(v, j + 0, 64);
            int s1 = __shfl(v, j + 1, 64);
            int s2 = __shfl(v, j + 2, 64);
            int s3 = __shfl(v, j + 3, 64);
            float g0 = zp[(s0 >> BKT_SHIFT) * N_CLASSES + lane];
            float g1 = zp[(s1 >> BKT_SHIFT) * N_CLASSES + lane];
            float g2 = zp[(s2 >> BKT_SHIFT) * N_CLASSES + lane];
            float g3 = zp[(s3 >> BKT_SHIFT) * N_CLASSES + lane];
            atomicAdd(&acc[(s0 & (BKT_NODES - 1)) * N_CLASSES + lane], g0);
            atomicAdd(&acc[(s1 & (BKT_NODES - 1)) * N_CLASSES + lane], g1);
            atomicAdd(&acc[(s2 & (BKT_NODES - 1)) * N_CLASSES + lane], g2);
            atomicAdd(&acc[(s3 & (BKT_NODES - 1)) * N_CLASSES + lane], g3);
        }
        for (; j < cnt; j++) {
            int s0 = __shfl(v, j, 64);
            atomicAdd(&acc[(s0 & (BKT_NODES - 1)) * N_CLASSES + lane],
                      zp[(s0 >> BKT_SHIFT) * N_CLASSES + lane]);
        }
    }
    __syncthreads();

    const int node0 = blockIdx.x * BKT_NODES;
    for (int r = wid; r < BKT_NODES; r += 8) {
        const int node = node0 + r;
        if (node >= N_NODES) break;
        float a = acc[r * N_CLASSES + lane] + zp[node * N_CLASSES + lane]; // + self-loop
        float dinv = rsqrtf((float)deg[node]);
        float vv = a * dinv + b[lane];

        float m = vv;
#pragma unroll
        for (int off = 32; off > 0; off >>= 1)
            m = fmaxf(m, __shfl_xor(m, off, 64));
        float ex = __expf(vv - m);
        float l = ex;
#pragma unroll
        for (int off = 32; off > 0; off >>= 1)
            l += __shfl_xor(l, off, 64);

        out[node * N_CLASSES + lane] = vv - m - __logf(l);
    }
}

// ---------------------------------------------------------------------------
// Launch
// ---------------------------------------------------------------------------
extern "C" void kernel_launch(void* const* d_in, const int* in_sizes, int n_in,
                              void* d_out, int out_size, void* d_ws, size_t ws_size,
                              hipStream_t stream) {
    const float* x    = (const float*)d_in[0];
    const int*   edge = (const int*)d_in[1];   // [2,E]: src then dst
    const float* W    = (const float*)d_in[2];
    const float* b    = (const float*)d_in[3];
    float* out = (float*)d_out;

    char* ws = (char*)d_ws;
    int*   deg    = (int*)(ws);
    int*   bcnt   = (int*)(ws + OFF_BCNT);
    int*   binned = (int*)(ws + OFF_BINNED);
    float* zp     = (float*)(ws + OFF_ZP);     // ends at 34,012,160 B

    const int* srcv = edge;
    const int* dstv = edge + N_EDGES;

    init_kernel<<<(N_NODES + 255) / 256, 256, 0, stream>>>(deg, bcnt);
    count_deg_kernel<<<(N_EDGES + 255) / 256, 256, 0, stream>>>(dstv, deg);
    gemm_kernel<<<N_NODES / 32, 256, 0, stream>>>(x, W, deg, zp);
    bin_kernel<<<NBLK_A, 256, 0, stream>>>(srcv, dstv, bcnt, binned);
    agg_kernel<<<NB, 512, 0, stream>>>(deg, bcnt, binned, zp, b, out);
}

// Round 5
// 950.691 us; speedup vs baseline: 1.0134x; 1.0134x over previous
//
#include <hip/hip_runtime.h>
#include <hip/hip_bf16.h>
#include <math.h>

#define N_NODES   100000
#define N_EDGES   1600000
#define D_FEAT    128
#define N_CLASSES 64

#define BKT_SHIFT 7                     // 128 nodes per bucket
#define BKT_NODES 128
#define NB        782                   // ceil(100000/128)
#define CAP       2560                  // per-bucket capacity (avg 2048)
#define CHUNK     8192                  // edges per bin block
#define NBLK_A    ((N_EDGES + CHUNK - 1) / CHUNK)   // 196
#define ACC_STRIDE 65                   // 64 + 1: stride-4 ds_adds land conflict-free

// ws layout (total 34,012,160 B — proven safe in R4):
#define OFF_BCNT   400384
#define OFF_BINNED 404480
#define OFF_ZP     8412160

// ---------------------------------------------------------------------------
// K1: deg[i] = 1 (self-loop); bcnt[b] = 0
// ---------------------------------------------------------------------------
__global__ __launch_bounds__(256) void init_kernel(int* __restrict__ deg,
                                                   int* __restrict__ bcnt) {
    int i = blockIdx.x * 256 + threadIdx.x;
    if (i < N_NODES) deg[i] = 1;
    if (i < NB) bcnt[i] = 0;
}

// ---------------------------------------------------------------------------
// K2: deg[dst[e]] += 1  (in-degree histogram)
// ---------------------------------------------------------------------------
__global__ __launch_bounds__(256) void count_deg_kernel(const int* __restrict__ dst,
                                                        int* __restrict__ deg) {
    int e = blockIdx.x * 256 + threadIdx.x;
    if (e < N_EDGES) atomicAdd(&deg[dst[e]], 1);
}

// ---------------------------------------------------------------------------
// K3: zp[i][c] = rsqrt(deg[i]) * sum_k x[i][k]*W[c][k]
// ---------------------------------------------------------------------------
__global__ __launch_bounds__(256) void gemm_kernel(const float* __restrict__ x,
                                                   const float* __restrict__ W,
                                                   const int* __restrict__ deg,
                                                   float* __restrict__ zp) {
    __shared__ float Ws[N_CLASSES * 132];
    __shared__ float Xs[32 * D_FEAT];
    const int tid = threadIdx.x;

    for (int i = tid; i < N_CLASSES * D_FEAT; i += 256)
        Ws[(i >> 7) * 132 + (i & 127)] = W[i];

    const float4* __restrict__ x4 = (const float4*)(x + (size_t)blockIdx.x * 32 * D_FEAT);
    float4* Xs4 = (float4*)Xs;
    for (int i = tid; i < 32 * (D_FEAT / 4); i += 256)
        Xs4[i] = x4[i];
    __syncthreads();

    const int c  = tid & 63;
    const int w  = tid >> 6;
    const int rb = w * 8;
    float acc[8] = {0.f, 0.f, 0.f, 0.f, 0.f, 0.f, 0.f, 0.f};

#pragma unroll 4
    for (int k4 = 0; k4 < D_FEAT / 4; k4++) {
        float4 wv = *(const float4*)&Ws[c * 132 + k4 * 4];
#pragma unroll
        for (int r = 0; r < 8; r++) {
            float4 xv = *(const float4*)&Xs[(rb + r) * D_FEAT + k4 * 4];
            acc[r] += xv.x * wv.x;
            acc[r] += xv.y * wv.y;
            acc[r] += xv.z * wv.z;
            acc[r] += xv.w * wv.w;
        }
    }

    const int row0 = blockIdx.x * 32 + rb;
#pragma unroll
    for (int r = 0; r < 8; r++) {
        int row = row0 + r;
        float dinv = rsqrtf((float)deg[row]);
        zp[row * N_CLASSES + c] = acc[r] * dinv;
    }
}

// ---------------------------------------------------------------------------
// K4: bin edges into NB coarse buckets (contiguous per-block runs).
// ---------------------------------------------------------------------------
__global__ __launch_bounds__(256) void bin_kernel(const int* __restrict__ src,
                                                  const int* __restrict__ dst,
                                                  int* __restrict__ bcnt,
                                                  int* __restrict__ binned) {
    __shared__ int hist[NB];
    __shared__ int rbase[NB];
    const int tid = threadIdx.x;
    const int e0 = blockIdx.x * CHUNK;
    const int e1 = min(e0 + CHUNK, N_EDGES);

    for (int i = tid; i < NB; i += 256) hist[i] = 0;
    __syncthreads();

    for (int e = e0 + tid; e < e1; e += 256)
        atomicAdd(&hist[dst[e] >> BKT_SHIFT], 1);
    __syncthreads();

    for (int i = tid; i < NB; i += 256) {
        int h = hist[i];
        if (h) rbase[i] = atomicAdd(&bcnt[i], h);
        hist[i] = 0;                       // reuse as within-run cursor
    }
    __syncthreads();

    for (int e = e0 + tid; e < e1; e += 256) {
        int d = dst[e];
        int bkt = d >> BKT_SHIFT;
        int pos = atomicAdd(&hist[bkt], 1);
        int off = rbase[bkt] + pos;
        if (off < CAP)                     // memory guard (never taken in practice)
            binned[bkt * CAP + off] = (src[e] << BKT_SHIFT) | (d & (BKT_NODES - 1));
    }
}

// ---------------------------------------------------------------------------
// K5: per-bucket aggregation + fused bias/log-softmax.
//     float4 gathers: 64 lanes = 4 edges x 16 chunks -> 1 KB per vmem instr.
//     acc rows padded to 65 floats: the stride-4 scalar ds_adds from the 4
//     sub-groups land on disjoint mod-4 bank residues -> 2-way (free).
// ---------------------------------------------------------------------------
__global__ __launch_bounds__(512) void agg_kernel(const int* __restrict__ deg,
                                                  const int* __restrict__ bcnt,
                                                  const int* __restrict__ binned,
                                                  const float* __restrict__ zp,
                                                  const float* __restrict__ b,
                                                  float* __restrict__ out) {
    __shared__ float acc[BKT_NODES * ACC_STRIDE];   // 33,280 B
    const int tid  = threadIdx.x;
    const int lane = tid & 63;
    const int wid  = tid >> 6;                      // 0..7
    const int sub  = lane >> 4;                     // which of 4 edges
    const int q4   = (lane & 15) * 4;               // class chunk start

    for (int i = tid; i < BKT_NODES * ACC_STRIDE; i += 512) acc[i] = 0.f;
    __syncthreads();

    const int n    = min(bcnt[blockIdx.x], CAP);
    const int base = blockIdx.x * CAP;

    for (int eb = wid * 64; eb < n; eb += 512) {
        const int cnt = min(n - eb, 64);
        int v = (lane < cnt) ? binned[base + eb + lane] : 0;
#pragma unroll 4
        for (int j = 0; j < 16; j++) {
            const int eid = j * 4 + sub;
            // clamped broadcast -> load is unconditional (pipelines freely)
            int s = __shfl(v, min(eid, cnt - 1), 64);
            const int row  = s >> BKT_SHIFT;
            const int node = s & (BKT_NODES - 1);
            float4 g = *(const float4*)&zp[row * N_CLASSES + q4];
            if (eid < cnt) {
                float* a = &acc[node * ACC_STRIDE + q4];
                atomicAdd(&a[0], g.x);
                atomicAdd(&a[1], g.y);
                atomicAdd(&a[2], g.z);
                atomicAdd(&a[3], g.w);
            }
        }
    }
    __syncthreads();

    const int node0 = blockIdx.x * BKT_NODES;
    for (int r = wid; r < BKT_NODES; r += 8) {
        const int node = node0 + r;
        if (node >= N_NODES) break;
        float a = acc[r * ACC_STRIDE + lane] + zp[node * N_CLASSES + lane]; // + self-loop
        float dinv = rsqrtf((float)deg[node]);
        float vv = a * dinv + b[lane];

        float m = vv;
#pragma unroll
        for (int off = 32; off > 0; off >>= 1)
            m = fmaxf(m, __shfl_xor(m, off, 64));
        float ex = __expf(vv - m);
        float l = ex;
#pragma unroll
        for (int off = 32; off > 0; off >>= 1)
            l += __shfl_xor(l, off, 64);

        out[node * N_CLASSES + lane] = vv - m - __logf(l);
    }
}

// ---------------------------------------------------------------------------
// Launch
// ---------------------------------------------------------------------------
extern "C" void kernel_launch(void* const* d_in, const int* in_sizes, int n_in,
                              void* d_out, int out_size, void* d_ws, size_t ws_size,
                              hipStream_t stream) {
    const float* x    = (const float*)d_in[0];
    const int*   edge = (const int*)d_in[1];   // [2,E]: src then dst
    const float* W    = (const float*)d_in[2];
    const float* b    = (const float*)d_in[3];
    float* out = (float*)d_out;

    char* ws = (char*)d_ws;
    int*   deg    = (int*)(ws);
    int*   bcnt   = (int*)(ws + OFF_BCNT);
    int*   binned = (int*)(ws + OFF_BINNED);
    float* zp     = (float*)(ws + OFF_ZP);     // ends at 34,012,160 B

    const int* srcv = edge;
    const int* dstv = edge + N_EDGES;

    init_kernel<<<(N_NODES + 255) / 256, 256, 0, stream>>>(deg, bcnt);
    count_deg_kernel<<<(N_EDGES + 255) / 256, 256, 0, stream>>>(dstv, deg);
    gemm_kernel<<<N_NODES / 32, 256, 0, stream>>>(x, W, deg, zp);
    bin_kernel<<<NBLK_A, 256, 0, stream>>>(srcv, dstv, bcnt, binned);
    agg_kernel<<<NB, 512, 0, stream>>>(deg, bcnt, binned, zp, b, out);
}

// Round 6
// 311.407 us; speedup vs baseline: 3.0938x; 3.0529x over previous
//
#include <hip/hip_runtime.h>
#include <hip/hip_bf16.h>
#include <math.h>

#define N_NODES   100000
#define N_EDGES   1600000
#define D_FEAT    128
#define N_CLASSES 64

#define BKT_SHIFT 7                     // 128 nodes per bucket
#define BKT_NODES 128
#define NB        782                   // ceil(100000/128)
#define CAP       2560                  // per-bucket capacity (avg 2048)
#define CHUNK     8192                  // edges per bin block
#define NBLK_A    ((N_EDGES + CHUNK - 1) / CHUNK)   // 196

// ws layout (total 34,012,160 B — proven safe in R4/R5):
#define OFF_BCNT   400384
#define OFF_BINNED 404480
#define OFF_ZP     8412160

// ---------------------------------------------------------------------------
// K1: deg[i] = 1 (self-loop); bcnt[b] = 0
// ---------------------------------------------------------------------------
__global__ __launch_bounds__(256) void init_kernel(int* __restrict__ deg,
                                                   int* __restrict__ bcnt) {
    int i = blockIdx.x * 256 + threadIdx.x;
    if (i < N_NODES) deg[i] = 1;
    if (i < NB) bcnt[i] = 0;
}

// ---------------------------------------------------------------------------
// K2: deg[dst[e]] += 1  (in-degree histogram)
// ---------------------------------------------------------------------------
__global__ __launch_bounds__(256) void count_deg_kernel(const int* __restrict__ dst,
                                                        int* __restrict__ deg) {
    int e = blockIdx.x * 256 + threadIdx.x;
    if (e < N_EDGES) atomicAdd(&deg[dst[e]], 1);
}

// ---------------------------------------------------------------------------
// K3: zp[i][c] = rsqrt(deg[i]) * sum_k x[i][k]*W[c][k]
// ---------------------------------------------------------------------------
__global__ __launch_bounds__(256) void gemm_kernel(const float* __restrict__ x,
                                                   const float* __restrict__ W,
                                                   const int* __restrict__ deg,
                                                   float* __restrict__ zp) {
    __shared__ float Ws[N_CLASSES * 132];
    __shared__ float Xs[32 * D_FEAT];
    const int tid = threadIdx.x;

    for (int i = tid; i < N_CLASSES * D_FEAT; i += 256)
        Ws[(i >> 7) * 132 + (i & 127)] = W[i];

    const float4* __restrict__ x4 = (const float4*)(x + (size_t)blockIdx.x * 32 * D_FEAT);
    float4* Xs4 = (float4*)Xs;
    for (int i = tid; i < 32 * (D_FEAT / 4); i += 256)
        Xs4[i] = x4[i];
    __syncthreads();

    const int c  = tid & 63;
    const int w  = tid >> 6;
    const int rb = w * 8;
    float acc[8] = {0.f, 0.f, 0.f, 0.f, 0.f, 0.f, 0.f, 0.f};

#pragma unroll 4
    for (int k4 = 0; k4 < D_FEAT / 4; k4++) {
        float4 wv = *(const float4*)&Ws[c * 132 + k4 * 4];
#pragma unroll
        for (int r = 0; r < 8; r++) {
            float4 xv = *(const float4*)&Xs[(rb + r) * D_FEAT + k4 * 4];
            acc[r] += xv.x * wv.x;
            acc[r] += xv.y * wv.y;
            acc[r] += xv.z * wv.z;
            acc[r] += xv.w * wv.w;
        }
    }

    const int row0 = blockIdx.x * 32 + rb;
#pragma unroll
    for (int r = 0; r < 8; r++) {
        int row = row0 + r;
        float dinv = rsqrtf((float)deg[row]);
        zp[row * N_CLASSES + c] = acc[r] * dinv;
    }
}

// ---------------------------------------------------------------------------
// K4: bin edges into NB coarse buckets (contiguous per-block runs).
// ---------------------------------------------------------------------------
__global__ __launch_bounds__(256) void bin_kernel(const int* __restrict__ src,
                                                  const int* __restrict__ dst,
                                                  int* __restrict__ bcnt,
                                                  int* __restrict__ binned) {
    __shared__ int hist[NB];
    __shared__ int rbase[NB];
    const int tid = threadIdx.x;
    const int e0 = blockIdx.x * CHUNK;
    const int e1 = min(e0 + CHUNK, N_EDGES);

    for (int i = tid; i < NB; i += 256) hist[i] = 0;
    __syncthreads();

    for (int e = e0 + tid; e < e1; e += 256)
        atomicAdd(&hist[dst[e] >> BKT_SHIFT], 1);
    __syncthreads();

    for (int i = tid; i < NB; i += 256) {
        int h = hist[i];
        if (h) rbase[i] = atomicAdd(&bcnt[i], h);
        hist[i] = 0;                       // reuse as within-run cursor
    }
    __syncthreads();

    for (int e = e0 + tid; e < e1; e += 256) {
        int d = dst[e];
        int bkt = d >> BKT_SHIFT;
        int pos = atomicAdd(&hist[bkt], 1);
        int off = rbase[bkt] + pos;
        if (off < CAP)                     // memory guard (never taken in practice)
            binned[bkt * CAP + off] = (src[e] << BKT_SHIFT) | (d & (BKT_NODES - 1));
    }
}

// ---------------------------------------------------------------------------
// K5: per-bucket aggregation, ATOMIC-FREE accumulate.
//     Phase A-C: locally sort bucket entries by node in LDS
//                (histogram -> wave scan -> scatter; int atomics only, ~4K).
//     Phase D:   one wave per node (8 nodes in flight per block):
//                lane = (sub = which-of-4-edges, q4 = 4-class chunk);
//                1 KB float4 gathers, register accumulate, shfl combine,
//                fused bias + log-softmax, one float4 store per node row.
// ---------------------------------------------------------------------------
__global__ __launch_bounds__(512) void agg_kernel(const int* __restrict__ deg,
                                                  const int* __restrict__ bcnt,
                                                  const int* __restrict__ binned,
                                                  const float* __restrict__ zp,
                                                  const float* __restrict__ b,
                                                  float* __restrict__ out) {
    __shared__ int sorted_s[CAP];               // 10,240 B: src rows, grouped by node
    __shared__ int hcnt[BKT_NODES];
    __shared__ int cur[BKT_NODES];
    __shared__ int rowstart[BKT_NODES + 1];

    const int tid  = threadIdx.x;
    const int lane = tid & 63;
    const int wid  = tid >> 6;                  // 0..7

    if (tid < BKT_NODES) { hcnt[tid] = 0; cur[tid] = 0; }
    __syncthreads();

    const int n    = min(bcnt[blockIdx.x], CAP);
    const int base = blockIdx.x * CAP;

    // Phase A: histogram over the 128 local nodes
    for (int i = tid; i < n; i += 512)
        atomicAdd(&hcnt[binned[base + i] & (BKT_NODES - 1)], 1);
    __syncthreads();

    // Phase B: inclusive scan of hcnt -> rowstart[1..128], rowstart[0]=0 (wave 0)
    if (wid == 0) {
        int v0 = hcnt[lane];
        int v1 = hcnt[64 + lane];
        int s0 = v0;
#pragma unroll
        for (int off = 1; off < 64; off <<= 1) {
            int t = __shfl_up(s0, off, 64);
            if (lane >= off) s0 += t;
        }
        int tot0 = __shfl(s0, 63, 64);
        int s1 = v1;
#pragma unroll
        for (int off = 1; off < 64; off <<= 1) {
            int t = __shfl_up(s1, off, 64);
            if (lane >= off) s1 += t;
        }
        s1 += tot0;
        if (lane == 0) rowstart[0] = 0;
        rowstart[1 + lane]  = s0;
        rowstart[65 + lane] = s1;
    }
    __syncthreads();

    // Phase C: scatter src-rows into node-grouped order
    for (int i = tid; i < n; i += 512) {
        int v  = binned[base + i];
        int nd = v & (BKT_NODES - 1);
        int p  = atomicAdd(&cur[nd], 1);
        sorted_s[rowstart[nd] + p] = v >> BKT_SHIFT;
    }
    __syncthreads();

    // Phase D: per-node register accumulation + fused epilogue
    const int sub = lane >> 4;                  // edge slot 0..3
    const int q4  = (lane & 15) * 4;            // class chunk start
    const int node0 = blockIdx.x * BKT_NODES;

    for (int r = wid; r < BKT_NODES; r += 8) {
        const int node = node0 + r;
        if (node >= N_NODES) break;
        const int start = rowstart[r];
        const int cnt   = rowstart[r + 1] - start;

        float4 a4 = make_float4(0.f, 0.f, 0.f, 0.f);
        const int jmax = (cnt + 3) >> 2;
        for (int j = 0; j < jmax; j++) {
            const int eid = j * 4 + sub;
            const int row = sorted_s[start + min(eid, cnt - 1)];
            const float4 g = *(const float4*)&zp[row * N_CLASSES + q4];
            if (eid < cnt) {
                a4.x += g.x; a4.y += g.y; a4.z += g.z; a4.w += g.w;
            }
        }
        // combine the 4 edge-slots (xor 16, 32 across the wave)
#pragma unroll
        for (int mask = 16; mask <= 32; mask <<= 1) {
            a4.x += __shfl_xor(a4.x, mask, 64);
            a4.y += __shfl_xor(a4.y, mask, 64);
            a4.z += __shfl_xor(a4.z, mask, 64);
            a4.w += __shfl_xor(a4.w, mask, 64);
        }
        // self-loop
        const float4 sf = *(const float4*)&zp[node * N_CLASSES + q4];
        a4.x += sf.x; a4.y += sf.y; a4.z += sf.z; a4.w += sf.w;

        const float dinv = rsqrtf((float)deg[node]);
        const float4 bb = *(const float4*)&b[q4];
        float v0 = a4.x * dinv + bb.x;
        float v1 = a4.y * dinv + bb.y;
        float v2 = a4.z * dinv + bb.z;
        float v3 = a4.w * dinv + bb.w;

        float m = fmaxf(fmaxf(v0, v1), fmaxf(v2, v3));
#pragma unroll
        for (int mask = 1; mask <= 8; mask <<= 1)
            m = fmaxf(m, __shfl_xor(m, mask, 64));
        float l = __expf(v0 - m) + __expf(v1 - m) + __expf(v2 - m) + __expf(v3 - m);
#pragma unroll
        for (int mask = 1; mask <= 8; mask <<= 1)
            l += __shfl_xor(l, mask, 64);
        const float lg = __logf(l);

        if (sub == 0) {
            float4 o;
            o.x = v0 - m - lg; o.y = v1 - m - lg; o.z = v2 - m - lg; o.w = v3 - m - lg;
            *(float4*)&out[node * N_CLASSES + q4] = o;
        }
    }
}

// ---------------------------------------------------------------------------
// Launch
// ---------------------------------------------------------------------------
extern "C" void kernel_launch(void* const* d_in, const int* in_sizes, int n_in,
                              void* d_out, int out_size, void* d_ws, size_t ws_size,
                              hipStream_t stream) {
    const float* x    = (const float*)d_in[0];
    const int*   edge = (const int*)d_in[1];   // [2,E]: src then dst
    const float* W    = (const float*)d_in[2];
    const float* b    = (const float*)d_in[3];
    float* out = (float*)d_out;

    char* ws = (char*)d_ws;
    int*   deg    = (int*)(ws);
    int*   bcnt   = (int*)(ws + OFF_BCNT);
    int*   binned = (int*)(ws + OFF_BINNED);
    float* zp     = (float*)(ws + OFF_ZP);     // ends at 34,012,160 B

    const int* srcv = edge;
    const int* dstv = edge + N_EDGES;

    init_kernel<<<(N_NODES + 255) / 256, 256, 0, stream>>>(deg, bcnt);
    count_deg_kernel<<<(N_EDGES + 255) / 256, 256, 0, stream>>>(dstv, deg);
    gemm_kernel<<<N_NODES / 32, 256, 0, stream>>>(x, W, deg, zp);
    bin_kernel<<<NBLK_A, 256, 0, stream>>>(srcv, dstv, bcnt, binned);
    agg_kernel<<<NB, 512, 0, stream>>>(deg, bcnt, binned, zp, b, out);
}

// Round 7
// 259.828 us; speedup vs baseline: 3.7079x; 1.1985x over previous
//
#include <hip/hip_runtime.h>
#include <hip/hip_bf16.h>
#include <math.h>

#define N_NODES   100000
#define N_EDGES   1600000
#define D_FEAT    128
#define N_CLASSES 64

#define BKT_SHIFT 7                     // 128 nodes per bucket
#define BKT_NODES 128
#define NB        782                   // ceil(100000/128)
#define CAP       2560                  // per-bucket capacity (avg 2048)
#define CHUNK     4096                  // edges per bin block
#define NBLK_A    ((N_EDGES + CHUNK - 1) / CHUNK)   // 391
#define NBLK_G    ((N_NODES + 63) / 64)             // 1563

// ws layout (total 34,012,160 B — proven safe in R4-R6):
#define OFF_BCNT   400384
#define OFF_BINNED 404480
#define OFF_ZP     8412160

typedef __attribute__((ext_vector_type(8))) short bf16x8;
typedef __attribute__((ext_vector_type(4))) float f32x4;

static __device__ inline unsigned f2bf1(float f) {
    unsigned u = __float_as_uint(f);
    return (u + 0x7FFF + ((u >> 16) & 1)) >> 16;     // RNE
}
static __device__ inline unsigned pack2(float a, float b) {
    return f2bf1(a) | (f2bf1(b) << 16);
}

// ---------------------------------------------------------------------------
// K1: deg[i] = 1 (self-loop); bcnt[b] = 0
// ---------------------------------------------------------------------------
__global__ __launch_bounds__(256) void init_kernel(int* __restrict__ deg,
                                                   int* __restrict__ bcnt) {
    int i = blockIdx.x * 256 + threadIdx.x;
    if (i < N_NODES) deg[i] = 1;
    if (i < NB) bcnt[i] = 0;
}

// ---------------------------------------------------------------------------
// K2: bin edges into NB coarse buckets + in-degree histogram (folded).
// ---------------------------------------------------------------------------
__global__ __launch_bounds__(256) void bin_kernel(const int* __restrict__ src,
                                                  const int* __restrict__ dst,
                                                  int* __restrict__ deg,
                                                  int* __restrict__ bcnt,
                                                  int* __restrict__ binned) {
    __shared__ int hist[NB];
    __shared__ int rbase[NB];
    const int tid = threadIdx.x;
    const int e0 = blockIdx.x * CHUNK;
    const int e1 = min(e0 + CHUNK, N_EDGES);

    for (int i = tid; i < NB; i += 256) hist[i] = 0;
    __syncthreads();

    for (int e = e0 + tid; e < e1; e += 256) {
        int d = dst[e];
        atomicAdd(&deg[d], 1);                 // folded count_deg
        atomicAdd(&hist[d >> BKT_SHIFT], 1);
    }
    __syncthreads();

    for (int i = tid; i < NB; i += 256) {
        int h = hist[i];
        if (h) rbase[i] = atomicAdd(&bcnt[i], h);
        hist[i] = 0;                           // reuse as within-run cursor
    }
    __syncthreads();

    for (int e = e0 + tid; e < e1; e += 256) {
        int d = dst[e];
        int bkt = d >> BKT_SHIFT;
        int pos = atomicAdd(&hist[bkt], 1);
        int off = rbase[bkt] + pos;
        if (off < CAP)                         // memory guard
            binned[bkt * CAP + off] = (src[e] << BKT_SHIFT) | (d & (BKT_NODES - 1));
    }
}

// ---------------------------------------------------------------------------
// K3: zp[i][c] = rsqrt(deg[i]) * (x @ W^T)[i][c]  via bf16 MFMA.
//     64 rows/block, 4 waves; wave = 16 rows x 64 cols.
//     A frag: X[m=lane&15][k=(lane>>4)*8+j]; B frag: W[n=lane&15][k=...]
//     C/D: col=lane&15, row=(lane>>4)*4+reg. LDS rows padded to 136 bf16.
// ---------------------------------------------------------------------------
__global__ __launch_bounds__(256) void gemm_kernel(const float* __restrict__ x,
                                                   const float* __restrict__ W,
                                                   const int* __restrict__ deg,
                                                   float* __restrict__ zp) {
    __shared__ short Xb[64 * 136];
    __shared__ short Wb[64 * 136];
    const int tid  = threadIdx.x;
    const int row0 = blockIdx.x * 64;

    // stage W (64x128 fp32 -> bf16)
    const float4* __restrict__ W4 = (const float4*)W;
    for (int idx = tid; idx < 64 * 32; idx += 256) {
        int n = idx >> 5, k4 = idx & 31;
        float4 v = W4[idx];
        uint2 p;
        p.x = pack2(v.x, v.y);
        p.y = pack2(v.z, v.w);
        *(uint2*)&Wb[n * 136 + k4 * 4] = p;
    }
    // stage X tile (rows clamped at tail)
    const float4* __restrict__ x4 = (const float4*)x;
    for (int idx = tid; idx < 64 * 32; idx += 256) {
        int r = idx >> 5, k4 = idx & 31;
        int gr = min(row0 + r, N_NODES - 1);
        float4 v = x4[gr * 32 + k4];
        uint2 p;
        p.x = pack2(v.x, v.y);
        p.y = pack2(v.z, v.w);
        *(uint2*)&Xb[r * 136 + k4 * 4] = p;
    }
    __syncthreads();

    const int lane = tid & 63;
    const int wv   = tid >> 6;
    const int m    = lane & 15;
    const int half = lane >> 4;

    bf16x8 bfr[4][4];                       // [k-tile][n-tile]
#pragma unroll
    for (int t = 0; t < 4; t++)
#pragma unroll
        for (int j = 0; j < 4; j++)
            bfr[t][j] = *(bf16x8*)&Wb[(j * 16 + m) * 136 + t * 32 + half * 8];

    f32x4 acc[4];
#pragma unroll
    for (int j = 0; j < 4; j++) acc[j] = (f32x4){0.f, 0.f, 0.f, 0.f};

#pragma unroll
    for (int t = 0; t < 4; t++) {
        bf16x8 a = *(bf16x8*)&Xb[(wv * 16 + m) * 136 + t * 32 + half * 8];
#pragma unroll
        for (int j = 0; j < 4; j++)
            acc[j] = __builtin_amdgcn_mfma_f32_16x16x32_bf16(a, bfr[t][j], acc[j], 0, 0, 0);
    }

#pragma unroll
    for (int r = 0; r < 4; r++) {
        const int row = row0 + wv * 16 + half * 4 + r;
        if (row < N_NODES) {
            const float dinv = rsqrtf((float)deg[row]);
#pragma unroll
            for (int j = 0; j < 4; j++)
                zp[row * N_CLASSES + j * 16 + m] = acc[j][r] * dinv;
        }
    }
}

// ---------------------------------------------------------------------------
// K4: per-bucket aggregation, atomic-free accumulate (unchanged from R6).
// ---------------------------------------------------------------------------
__global__ __launch_bounds__(512) void agg_kernel(const int* __restrict__ deg,
                                                  const int* __restrict__ bcnt,
                                                  const int* __restrict__ binned,
                                                  const float* __restrict__ zp,
                                                  const float* __restrict__ b,
                                                  float* __restrict__ out) {
    __shared__ int sorted_s[CAP];               // src rows, grouped by node
    __shared__ int hcnt[BKT_NODES];
    __shared__ int cur[BKT_NODES];
    __shared__ int rowstart[BKT_NODES + 1];

    const int tid  = threadIdx.x;
    const int lane = tid & 63;
    const int wid  = tid >> 6;                  // 0..7

    if (tid < BKT_NODES) { hcnt[tid] = 0; cur[tid] = 0; }
    __syncthreads();

    const int n    = min(bcnt[blockIdx.x], CAP);
    const int base = blockIdx.x * CAP;

    // Phase A: histogram over the 128 local nodes
    for (int i = tid; i < n; i += 512)
        atomicAdd(&hcnt[binned[base + i] & (BKT_NODES - 1)], 1);
    __syncthreads();

    // Phase B: inclusive scan of hcnt -> rowstart (wave 0)
    if (wid == 0) {
        int v0 = hcnt[lane];
        int v1 = hcnt[64 + lane];
        int s0 = v0;
#pragma unroll
        for (int off = 1; off < 64; off <<= 1) {
            int t = __shfl_up(s0, off, 64);
            if (lane >= off) s0 += t;
        }
        int tot0 = __shfl(s0, 63, 64);
        int s1 = v1;
#pragma unroll
        for (int off = 1; off < 64; off <<= 1) {
            int t = __shfl_up(s1, off, 64);
            if (lane >= off) s1 += t;
        }
        s1 += tot0;
        if (lane == 0) rowstart[0] = 0;
        rowstart[1 + lane]  = s0;
        rowstart[65 + lane] = s1;
    }
    __syncthreads();

    // Phase C: scatter src-rows into node-grouped order
    for (int i = tid; i < n; i += 512) {
        int v  = binned[base + i];
        int nd = v & (BKT_NODES - 1);
        int p  = atomicAdd(&cur[nd], 1);
        sorted_s[rowstart[nd] + p] = v >> BKT_SHIFT;
    }
    __syncthreads();

    // Phase D: per-node register accumulation + fused epilogue
    const int sub = lane >> 4;                  // edge slot 0..3
    const int q4  = (lane & 15) * 4;            // class chunk start
    const int node0 = blockIdx.x * BKT_NODES;

    for (int r = wid; r < BKT_NODES; r += 8) {
        const int node = node0 + r;
        if (node >= N_NODES) break;
        const int start = rowstart[r];
        const int cnt   = rowstart[r + 1] - start;

        float4 a4 = make_float4(0.f, 0.f, 0.f, 0.f);
        const int jmax = (cnt + 3) >> 2;
        for (int j = 0; j < jmax; j++) {
            const int eid = j * 4 + sub;
            const int row = sorted_s[start + min(eid, cnt - 1)];
            const float4 g = *(const float4*)&zp[row * N_CLASSES + q4];
            if (eid < cnt) {
                a4.x += g.x; a4.y += g.y; a4.z += g.z; a4.w += g.w;
            }
        }
#pragma unroll
        for (int mask = 16; mask <= 32; mask <<= 1) {
            a4.x += __shfl_xor(a4.x, mask, 64);
            a4.y += __shfl_xor(a4.y, mask, 64);
            a4.z += __shfl_xor(a4.z, mask, 64);
            a4.w += __shfl_xor(a4.w, mask, 64);
        }
        const float4 sf = *(const float4*)&zp[node * N_CLASSES + q4];
        a4.x += sf.x; a4.y += sf.y; a4.z += sf.z; a4.w += sf.w;

        const float dinv = rsqrtf((float)deg[node]);
        const float4 bb = *(const float4*)&b[q4];
        float v0 = a4.x * dinv + bb.x;
        float v1 = a4.y * dinv + bb.y;
        float v2 = a4.z * dinv + bb.z;
        float v3 = a4.w * dinv + bb.w;

        float m = fmaxf(fmaxf(v0, v1), fmaxf(v2, v3));
#pragma unroll
        for (int mask = 1; mask <= 8; mask <<= 1)
            m = fmaxf(m, __shfl_xor(m, mask, 64));
        float l = __expf(v0 - m) + __expf(v1 - m) + __expf(v2 - m) + __expf(v3 - m);
#pragma unroll
        for (int mask = 1; mask <= 8; mask <<= 1)
            l += __shfl_xor(l, mask, 64);
        const float lg = __logf(l);

        if (sub == 0) {
            float4 o;
            o.x = v0 - m - lg; o.y = v1 - m - lg; o.z = v2 - m - lg; o.w = v3 - m - lg;
            *(float4*)&out[node * N_CLASSES + q4] = o;
        }
    }
}

// ---------------------------------------------------------------------------
// Launch
// ---------------------------------------------------------------------------
extern "C" void kernel_launch(void* const* d_in, const int* in_sizes, int n_in,
                              void* d_out, int out_size, void* d_ws, size_t ws_size,
                              hipStream_t stream) {
    const float* x    = (const float*)d_in[0];
    const int*   edge = (const int*)d_in[1];   // [2,E]: src then dst
    const float* W    = (const float*)d_in[2];
    const float* b    = (const float*)d_in[3];
    float* out = (float*)d_out;

    char* ws = (char*)d_ws;
    int*   deg    = (int*)(ws);
    int*   bcnt   = (int*)(ws + OFF_BCNT);
    int*   binned = (int*)(ws + OFF_BINNED);
    float* zp     = (float*)(ws + OFF_ZP);     // ends at 34,012,160 B

    const int* srcv = edge;
    const int* dstv = edge + N_EDGES;

    init_kernel<<<(N_NODES + 255) / 256, 256, 0, stream>>>(deg, bcnt);
    bin_kernel<<<NBLK_A, 256, 0, stream>>>(srcv, dstv, deg, bcnt, binned);
    gemm_kernel<<<NBLK_G, 256, 0, stream>>>(x, W, deg, zp);
    agg_kernel<<<NB, 512, 0, stream>>>(deg, bcnt, binned, zp, b, out);
}

// Round 8
// 213.878 us; speedup vs baseline: 4.5045x; 1.2148x over previous
//
#include <hip/hip_runtime.h>
#include <hip/hip_bf16.h>
#include <math.h>

#define N_NODES   100000
#define N_EDGES   1600000
#define D_FEAT    128
#define N_CLASSES 64

#define BKT_SHIFT 7                     // 128 nodes per bucket
#define BKT_NODES 128
#define NB        782                   // ceil(100000/128)
#define CAP       2560                  // per-bucket capacity (avg 2048)
#define CHUNK     4096                  // edges per bin block
#define NBLK_A    ((N_EDGES + CHUNK - 1) / CHUNK)   // 391
#define NBLK_G    ((N_NODES + 63) / 64)             // 1563

// ws layout (total 34,012,160 B — proven safe R4-R7):
//   meta   @ 0          (400,000 B)  start|(indeg<<21), start<2^21, indeg<=2047
//   bcnt   @ 400,384    (3,128 B)
//   binned @ 404,480    (8,007,680 B)  pass1: (src<<7)|local; pass2: grouped src
//   zp     @ 8,412,160  (25,600,000 B)
#define OFF_BCNT   400384
#define OFF_BINNED 404480
#define OFF_ZP     8412160

typedef __attribute__((ext_vector_type(8))) short bf16x8;
typedef __attribute__((ext_vector_type(4))) float f32x4;

static __device__ inline unsigned f2bf1(float f) {
    unsigned u = __float_as_uint(f);
    return (u + 0x7FFF + ((u >> 16) & 1)) >> 16;     // RNE
}
static __device__ inline unsigned pack2(float a, float b) {
    return f2bf1(a) | (f2bf1(b) << 16);
}

// ---------------------------------------------------------------------------
// K1: bcnt[b] = 0
// ---------------------------------------------------------------------------
__global__ __launch_bounds__(256) void init_kernel(int* __restrict__ bcnt) {
    int i = blockIdx.x * 256 + threadIdx.x;
    if (i < NB) bcnt[i] = 0;
}

// ---------------------------------------------------------------------------
// K2: bin edges into NB coarse buckets (contiguous per-block runs).
//     No deg atomics (degree comes free from sortdeg's histogram).
// ---------------------------------------------------------------------------
__global__ __launch_bounds__(512) void bin_kernel(const int* __restrict__ src,
                                                  const int* __restrict__ dst,
                                                  int* __restrict__ bcnt,
                                                  int* __restrict__ binned) {
    __shared__ int hist[NB];
    __shared__ int rbase[NB];
    const int tid = threadIdx.x;
    const int e0 = blockIdx.x * CHUNK;
    const int e1 = min(e0 + CHUNK, N_EDGES);

    for (int i = tid; i < NB; i += 512) hist[i] = 0;
    __syncthreads();

    for (int e = e0 + tid; e < e1; e += 512)
        atomicAdd(&hist[dst[e] >> BKT_SHIFT], 1);
    __syncthreads();

    for (int i = tid; i < NB; i += 512) {
        int h = hist[i];
        if (h) rbase[i] = atomicAdd(&bcnt[i], h);
        hist[i] = 0;                           // reuse as within-run cursor
    }
    __syncthreads();

    for (int e = e0 + tid; e < e1; e += 512) {
        int d = dst[e];
        int bkt = d >> BKT_SHIFT;
        int pos = atomicAdd(&hist[bkt], 1);
        int off = rbase[bkt] + pos;
        if (off < CAP)                         // memory guard
            binned[bkt * CAP + off] = (src[e] << BKT_SHIFT) | (d & (BKT_NODES - 1));
    }
}

// ---------------------------------------------------------------------------
// K3: per-bucket in-place sort-by-node + degree metadata.
//     Load run -> LDS; histogram (= in-degree, free!); wave scan; scatter
//     grouped src-rows back into the SAME binned region (dense writes).
//     meta[node] = absolute_start | (indeg << 21).
// ---------------------------------------------------------------------------
__global__ __launch_bounds__(512) void sortdeg_kernel(const int* __restrict__ bcnt,
                                                      int* __restrict__ binned,
                                                      int* __restrict__ meta) {
    __shared__ int buf[CAP];
    __shared__ int hcnt[BKT_NODES];
    __shared__ int cur[BKT_NODES];
    __shared__ int rowstart[BKT_NODES + 1];

    const int tid  = threadIdx.x;
    const int lane = tid & 63;
    const int wid  = tid >> 6;

    if (tid < BKT_NODES) { hcnt[tid] = 0; cur[tid] = 0; }
    __syncthreads();

    const int n    = min(bcnt[blockIdx.x], CAP);
    const int base = blockIdx.x * CAP;

    // load run + histogram
    for (int i = tid; i < n; i += 512) {
        int v = binned[base + i];
        buf[i] = v;
        atomicAdd(&hcnt[v & (BKT_NODES - 1)], 1);
    }
    __syncthreads();

    // wave-0 scan of 128 counts -> rowstart
    if (wid == 0) {
        int v0 = hcnt[lane];
        int v1 = hcnt[64 + lane];
        int s0 = v0;
#pragma unroll
        for (int off = 1; off < 64; off <<= 1) {
            int t = __shfl_up(s0, off, 64);
            if (lane >= off) s0 += t;
        }
        int tot0 = __shfl(s0, 63, 64);
        int s1 = v1;
#pragma unroll
        for (int off = 1; off < 64; off <<= 1) {
            int t = __shfl_up(s1, off, 64);
            if (lane >= off) s1 += t;
        }
        s1 += tot0;
        if (lane == 0) rowstart[0] = 0;
        rowstart[1 + lane]  = s0;
        rowstart[65 + lane] = s1;
    }
    __syncthreads();

    // scatter grouped src-rows back (in place; reads are all in buf already)
    for (int i = tid; i < n; i += 512) {
        int v  = buf[i];
        int nd = v & (BKT_NODES - 1);
        int p  = atomicAdd(&cur[nd], 1);
        binned[base + rowstart[nd] + p] = v >> BKT_SHIFT;
    }

    // metadata: absolute start + in-degree
    if (tid < BKT_NODES) {
        int node = blockIdx.x * BKT_NODES + tid;
        if (node < N_NODES) {
            int st = base + rowstart[tid];
            int dg = min(hcnt[tid], 2047);
            meta[node] = st | (dg << 21);
        }
    }
}

// ---------------------------------------------------------------------------
// K4: zp[i][c] = rsqrt(indeg[i]+1) * (x @ W^T)[i][c]  via bf16 MFMA.
// ---------------------------------------------------------------------------
__global__ __launch_bounds__(256) void gemm_kernel(const float* __restrict__ x,
                                                   const float* __restrict__ W,
                                                   const int* __restrict__ meta,
                                                   float* __restrict__ zp) {
    __shared__ short Xb[64 * 136];
    __shared__ short Wb[64 * 136];
    const int tid  = threadIdx.x;
    const int row0 = blockIdx.x * 64;

    const float4* __restrict__ W4 = (const float4*)W;
    for (int idx = tid; idx < 64 * 32; idx += 256) {
        int nn = idx >> 5, k4 = idx & 31;
        float4 v = W4[idx];
        uint2 p;
        p.x = pack2(v.x, v.y);
        p.y = pack2(v.z, v.w);
        *(uint2*)&Wb[nn * 136 + k4 * 4] = p;
    }
    const float4* __restrict__ x4 = (const float4*)x;
    for (int idx = tid; idx < 64 * 32; idx += 256) {
        int r = idx >> 5, k4 = idx & 31;
        int gr = min(row0 + r, N_NODES - 1);
        float4 v = x4[gr * 32 + k4];
        uint2 p;
        p.x = pack2(v.x, v.y);
        p.y = pack2(v.z, v.w);
        *(uint2*)&Xb[r * 136 + k4 * 4] = p;
    }
    __syncthreads();

    const int lane = tid & 63;
    const int wv   = tid >> 6;
    const int m    = lane & 15;
    const int half = lane >> 4;

    bf16x8 bfr[4][4];
#pragma unroll
    for (int t = 0; t < 4; t++)
#pragma unroll
        for (int j = 0; j < 4; j++)
            bfr[t][j] = *(bf16x8*)&Wb[(j * 16 + m) * 136 + t * 32 + half * 8];

    f32x4 acc[4];
#pragma unroll
    for (int j = 0; j < 4; j++) acc[j] = (f32x4){0.f, 0.f, 0.f, 0.f};

#pragma unroll
    for (int t = 0; t < 4; t++) {
        bf16x8 a = *(bf16x8*)&Xb[(wv * 16 + m) * 136 + t * 32 + half * 8];
#pragma unroll
        for (int j = 0; j < 4; j++)
            acc[j] = __builtin_amdgcn_mfma_f32_16x16x32_bf16(a, bfr[t][j], acc[j], 0, 0, 0);
    }

#pragma unroll
    for (int r = 0; r < 4; r++) {
        const int row = row0 + wv * 16 + half * 4 + r;
        if (row < N_NODES) {
            const int dg = ((unsigned)meta[row]) >> 21;
            const float dinv = rsqrtf((float)(dg + 1));
#pragma unroll
            for (int j = 0; j < 4; j++)
                zp[row * N_CLASSES + j * 16 + m] = acc[j][r] * dinv;
        }
    }
}

// ---------------------------------------------------------------------------
// K5: pure gather-accumulate + fused epilogue. One wave per node.
//     lane = (sub = edge slot 0..3, q4 = 4-class chunk); 1 KB per gather op.
// ---------------------------------------------------------------------------
__global__ __launch_bounds__(256) void agg_kernel(const int* __restrict__ meta,
                                                  const int* __restrict__ binned,
                                                  const float* __restrict__ zp,
                                                  const float* __restrict__ b,
                                                  float* __restrict__ out) {
    const int node = blockIdx.x * 4 + (threadIdx.x >> 6);
    const int lane = threadIdx.x & 63;
    const int sub  = lane >> 4;
    const int q4   = (lane & 15) * 4;

    const unsigned mv = (unsigned)meta[node];
    const int start = mv & 0x1FFFFF;
    const int cnt   = mv >> 21;

    float4 a4 = make_float4(0.f, 0.f, 0.f, 0.f);
    const int jmax = (cnt + 3) >> 2;
    for (int j = 0; j < jmax; j++) {
        const int eid = j * 4 + sub;
        const int row = binned[start + min(eid, cnt - 1)];
        const float4 g = *(const float4*)&zp[row * N_CLASSES + q4];
        if (eid < cnt) {
            a4.x += g.x; a4.y += g.y; a4.z += g.z; a4.w += g.w;
        }
    }
#pragma unroll
    for (int mask = 16; mask <= 32; mask <<= 1) {
        a4.x += __shfl_xor(a4.x, mask, 64);
        a4.y += __shfl_xor(a4.y, mask, 64);
        a4.z += __shfl_xor(a4.z, mask, 64);
        a4.w += __shfl_xor(a4.w, mask, 64);
    }
    const float4 sf = *(const float4*)&zp[node * N_CLASSES + q4];  // self-loop
    a4.x += sf.x; a4.y += sf.y; a4.z += sf.z; a4.w += sf.w;

    const float dinv = rsqrtf((float)(cnt + 1));
    const float4 bb = *(const float4*)&b[q4];
    float v0 = a4.x * dinv + bb.x;
    float v1 = a4.y * dinv + bb.y;
    float v2 = a4.z * dinv + bb.z;
    float v3 = a4.w * dinv + bb.w;

    float m = fmaxf(fmaxf(v0, v1), fmaxf(v2, v3));
#pragma unroll
    for (int mask = 1; mask <= 8; mask <<= 1)
        m = fmaxf(m, __shfl_xor(m, mask, 64));
    float l = __expf(v0 - m) + __expf(v1 - m) + __expf(v2 - m) + __expf(v3 - m);
#pragma unroll
    for (int mask = 1; mask <= 8; mask <<= 1)
        l += __shfl_xor(l, mask, 64);
    const float lg = __logf(l);

    if (sub == 0) {
        float4 o;
        o.x = v0 - m - lg; o.y = v1 - m - lg; o.z = v2 - m - lg; o.w = v3 - m - lg;
        *(float4*)&out[node * N_CLASSES + q4] = o;
    }
}

// ---------------------------------------------------------------------------
// Launch
// ---------------------------------------------------------------------------
extern "C" void kernel_launch(void* const* d_in, const int* in_sizes, int n_in,
                              void* d_out, int out_size, void* d_ws, size_t ws_size,
                              hipStream_t stream) {
    const float* x    = (const float*)d_in[0];
    const int*   edge = (const int*)d_in[1];   // [2,E]: src then dst
    const float* W    = (const float*)d_in[2];
    const float* b    = (const float*)d_in[3];
    float* out = (float*)d_out;

    char* ws = (char*)d_ws;
    int*   meta   = (int*)(ws);
    int*   bcnt   = (int*)(ws + OFF_BCNT);
    int*   binned = (int*)(ws + OFF_BINNED);
    float* zp     = (float*)(ws + OFF_ZP);     // ends at 34,012,160 B

    const int* srcv = edge;
    const int* dstv = edge + N_EDGES;

    init_kernel<<<(NB + 255) / 256, 256, 0, stream>>>(bcnt);
    bin_kernel<<<NBLK_A, 512, 0, stream>>>(srcv, dstv, bcnt, binned);
    sortdeg_kernel<<<NB, 512, 0, stream>>>(bcnt, binned, meta);
    gemm_kernel<<<NBLK_G, 256, 0, stream>>>(x, W, meta, zp);
    agg_kernel<<<N_NODES / 4, 256, 0, stream>>>(meta, binned, zp, b, out);
}

// Round 10
// 189.274 us; speedup vs baseline: 5.0901x; 1.1300x over previous
//
#include <hip/hip_runtime.h>
#include <hip/hip_bf16.h>
#include <hip/hip_fp16.h>
#include <math.h>

#define N_NODES   100000
#define N_EDGES   1600000
#define D_FEAT    128
#define N_CLASSES 64

#define BKT_SHIFT 7                     // 128 nodes per bucket
#define BKT_NODES 128
#define NB        782                   // ceil(100000/128)
#define CAP       2560                  // per-bucket capacity (avg 2048)
#define CHUNK     8192                  // edges per bin block
#define NBLK_A    ((N_EDGES + CHUNK - 1) / CHUNK)   // 196
#define NBLK_G    ((N_NODES + 63) / 64)             // 1563

// ws layout (max extent 21,212,160 B — well under proven 34 MB):
//   meta   @ 0          (400,000 B)  start|(indeg<<21)
//   bcnt   @ 400,384    (3,128 B)
//   binned @ 404,480    (8,007,680 B)
//   zp     @ 8,412,160  (12,800,000 B, fp16)
#define OFF_BCNT   400384
#define OFF_BINNED 404480
#define OFF_ZP     8412160

typedef __attribute__((ext_vector_type(8))) short bf16x8;
typedef __attribute__((ext_vector_type(4))) float f32x4;
typedef __attribute__((ext_vector_type(4))) unsigned int u32x4;

static __device__ inline unsigned f2bf1(float f) {
    unsigned u = __float_as_uint(f);
    return (u + 0x7FFF + ((u >> 16) & 1)) >> 16;     // RNE
}
static __device__ inline unsigned pack2(float a, float b) {
    return f2bf1(a) | (f2bf1(b) << 16);
}
static __device__ inline float2 h2f2(unsigned u) {
    __half2 h = *(__half2*)&u;
    return __half22float2(h);
}

// ---------------------------------------------------------------------------
// K1: bcnt[b] = 0
// ---------------------------------------------------------------------------
__global__ __launch_bounds__(256) void init_kernel(int* __restrict__ bcnt) {
    int i = blockIdx.x * 256 + threadIdx.x;
    if (i < NB) bcnt[i] = 0;
}

// ---------------------------------------------------------------------------
// K2: bin edges into NB coarse buckets (contiguous per-block runs).
//     1024 threads: 16 waves of latency hiding; ~10-edge runs per bucket.
// ---------------------------------------------------------------------------
__global__ __launch_bounds__(1024) void bin_kernel(const int* __restrict__ src,
                                                   const int* __restrict__ dst,
                                                   int* __restrict__ bcnt,
                                                   int* __restrict__ binned) {
    __shared__ int hist[NB];
    __shared__ int rbase[NB];
    const int tid = threadIdx.x;
    const int e0 = blockIdx.x * CHUNK;
    const int e1 = min(e0 + CHUNK, N_EDGES);

    for (int i = tid; i < NB; i += 1024) hist[i] = 0;
    __syncthreads();

    for (int e = e0 + tid; e < e1; e += 1024)
        atomicAdd(&hist[dst[e] >> BKT_SHIFT], 1);
    __syncthreads();

    for (int i = tid; i < NB; i += 1024) {
        int h = hist[i];
        if (h) rbase[i] = atomicAdd(&bcnt[i], h);
        hist[i] = 0;                           // reuse as within-run cursor
    }
    __syncthreads();

    for (int e = e0 + tid; e < e1; e += 1024) {
        int d = dst[e];
        int bkt = d >> BKT_SHIFT;
        int pos = atomicAdd(&hist[bkt], 1);
        int off = rbase[bkt] + pos;
        if (off < CAP)                         // memory guard
            binned[bkt * CAP + off] = (src[e] << BKT_SHIFT) | (d & (BKT_NODES - 1));
    }
}

// ---------------------------------------------------------------------------
// K3: per-bucket in-place sort-by-node + degree metadata.
// ---------------------------------------------------------------------------
__global__ __launch_bounds__(512) void sortdeg_kernel(const int* __restrict__ bcnt,
                                                      int* __restrict__ binned,
                                                      int* __restrict__ meta) {
    __shared__ int buf[CAP];
    __shared__ int hcnt[BKT_NODES];
    __shared__ int cur[BKT_NODES];
    __shared__ int rowstart[BKT_NODES + 1];

    const int tid  = threadIdx.x;
    const int lane = tid & 63;
    const int wid  = tid >> 6;

    if (tid < BKT_NODES) { hcnt[tid] = 0; cur[tid] = 0; }
    __syncthreads();

    const int n    = min(bcnt[blockIdx.x], CAP);
    const int base = blockIdx.x * CAP;

    for (int i = tid; i < n; i += 512) {
        int v = binned[base + i];
        buf[i] = v;
        atomicAdd(&hcnt[v & (BKT_NODES - 1)], 1);
    }
    __syncthreads();

    if (wid == 0) {
        int v0 = hcnt[lane];
        int v1 = hcnt[64 + lane];
        int s0 = v0;
#pragma unroll
        for (int off = 1; off < 64; off <<= 1) {
            int t = __shfl_up(s0, off, 64);
            if (lane >= off) s0 += t;
        }
        int tot0 = __shfl(s0, 63, 64);
        int s1 = v1;
#pragma unroll
        for (int off = 1; off < 64; off <<= 1) {
            int t = __shfl_up(s1, off, 64);
            if (lane >= off) s1 += t;
        }
        s1 += tot0;
        if (lane == 0) rowstart[0] = 0;
        rowstart[1 + lane]  = s0;
        rowstart[65 + lane] = s1;
    }
    __syncthreads();

    for (int i = tid; i < n; i += 512) {
        int v  = buf[i];
        int nd = v & (BKT_NODES - 1);
        int p  = atomicAdd(&cur[nd], 1);
        binned[base + rowstart[nd] + p] = v >> BKT_SHIFT;
    }

    if (tid < BKT_NODES) {
        int node = blockIdx.x * BKT_NODES + tid;
        if (node < N_NODES) {
            int st = base + rowstart[tid];
            int dg = min(hcnt[tid], 2047);
            meta[node] = st | (dg << 21);
        }
    }
}

// ---------------------------------------------------------------------------
// K4: zp[i][c] = rsqrt(indeg[i]+1) * (x @ W^T)[i][c]  via bf16 MFMA, fp16 out.
// ---------------------------------------------------------------------------
__global__ __launch_bounds__(256) void gemm_kernel(const float* __restrict__ x,
                                                   const float* __restrict__ W,
                                                   const int* __restrict__ meta,
                                                   __half* __restrict__ zp) {
    __shared__ short Xb[64 * 136];
    __shared__ short Wb[64 * 136];
    const int tid  = threadIdx.x;
    const int row0 = blockIdx.x * 64;

    const float4* __restrict__ W4 = (const float4*)W;
    for (int idx = tid; idx < 64 * 32; idx += 256) {
        int nn = idx >> 5, k4 = idx & 31;
        float4 v = W4[idx];
        uint2 p;
        p.x = pack2(v.x, v.y);
        p.y = pack2(v.z, v.w);
        *(uint2*)&Wb[nn * 136 + k4 * 4] = p;
    }
    const float4* __restrict__ x4 = (const float4*)x;
    for (int idx = tid; idx < 64 * 32; idx += 256) {
        int r = idx >> 5, k4 = idx & 31;
        int gr = min(row0 + r, N_NODES - 1);
        float4 v = x4[gr * 32 + k4];
        uint2 p;
        p.x = pack2(v.x, v.y);
        p.y = pack2(v.z, v.w);
        *(uint2*)&Xb[r * 136 + k4 * 4] = p;
    }
    __syncthreads();

    const int lane = tid & 63;
    const int wv   = tid >> 6;
    const int m    = lane & 15;
    const int half = lane >> 4;

    bf16x8 bfr[4][4];
#pragma unroll
    for (int t = 0; t < 4; t++)
#pragma unroll
        for (int j = 0; j < 4; j++)
            bfr[t][j] = *(bf16x8*)&Wb[(j * 16 + m) * 136 + t * 32 + half * 8];

    f32x4 acc[4];
#pragma unroll
    for (int j = 0; j < 4; j++) acc[j] = (f32x4){0.f, 0.f, 0.f, 0.f};

#pragma unroll
    for (int t = 0; t < 4; t++) {
        bf16x8 a = *(bf16x8*)&Xb[(wv * 16 + m) * 136 + t * 32 + half * 8];
#pragma unroll
        for (int j = 0; j < 4; j++)
            acc[j] = __builtin_amdgcn_mfma_f32_16x16x32_bf16(a, bfr[t][j], acc[j], 0, 0, 0);
    }

#pragma unroll
    for (int r = 0; r < 4; r++) {
        const int row = row0 + wv * 16 + half * 4 + r;
        if (row < N_NODES) {
            const int dg = ((unsigned)meta[row]) >> 21;
            const float dinv = rsqrtf((float)(dg + 1));
#pragma unroll
            for (int j = 0; j < 4; j++)
                zp[row * N_CLASSES + j * 16 + m] = __float2half(acc[j][r] * dinv);
        }
    }
}

// ---------------------------------------------------------------------------
// K5: gather-accumulate + fused epilogue. One wave per node.
//     lane = (sub = edge slot 0..7, o8 = 8-class chunk); fp16 rows = 128 B;
//     per vmem instruction: 8 edges x 128 B = 1 KB. fp32 accumulate.
// ---------------------------------------------------------------------------
__global__ __launch_bounds__(256) void agg_kernel(const int* __restrict__ meta,
                                                  const int* __restrict__ binned,
                                                  const __half* __restrict__ zp,
                                                  const float* __restrict__ b,
                                                  float* __restrict__ out) {
    const int node = blockIdx.x * 4 + (threadIdx.x >> 6);
    const int lane = threadIdx.x & 63;
    const int sub  = lane >> 3;                 // edge slot 0..7
    const int o8   = (lane & 7) * 8;            // class octet start

    const unsigned mv = (unsigned)meta[node];
    const int start = mv & 0x1FFFFF;
    const int cnt   = mv >> 21;

    float a[8] = {0.f, 0.f, 0.f, 0.f, 0.f, 0.f, 0.f, 0.f};
    const int jmax = (cnt + 7) >> 3;
    for (int j = 0; j < jmax; j++) {
        const int eid = j * 8 + sub;
        const int row = binned[start + min(eid, cnt - 1)];
        const u32x4 g = *(const u32x4*)&zp[row * N_CLASSES + o8];
        if (eid < cnt) {
#pragma unroll
            for (int k = 0; k < 4; k++) {
                float2 f = h2f2(g[k]);
                a[2 * k]     += f.x;
                a[2 * k + 1] += f.y;
            }
        }
    }
    // combine the 8 edge slots (xor 8,16,32): each octet-lane ends with full sums
#pragma unroll
    for (int mask = 8; mask <= 32; mask <<= 1)
#pragma unroll
        for (int k = 0; k < 8; k++)
            a[k] += __shfl_xor(a[k], mask, 64);

    // self-loop (same o8 on every sub group — redundant but harmless)
    const u32x4 sg = *(const u32x4*)&zp[node * N_CLASSES + o8];
#pragma unroll
    for (int k = 0; k < 4; k++) {
        float2 f = h2f2(sg[k]);
        a[2 * k]     += f.x;
        a[2 * k + 1] += f.y;
    }

    const float dinv = rsqrtf((float)(cnt + 1));
    float v[8];
#pragma unroll
    for (int k = 0; k < 8; k++) v[k] = a[k] * dinv + b[o8 + k];

    // max/sum over 8 local + the 8 octet lanes (masks 1,2,4 stay in-octet)
    float m = v[0];
#pragma unroll
    for (int k = 1; k < 8; k++) m = fmaxf(m, v[k]);
#pragma unroll
    for (int mask = 1; mask <= 4; mask <<= 1)
        m = fmaxf(m, __shfl_xor(m, mask, 64));
    float l = 0.f;
#pragma unroll
    for (int k = 0; k < 8; k++) l += __expf(v[k] - m);
#pragma unroll
    for (int mask = 1; mask <= 4; mask <<= 1)
        l += __shfl_xor(l, mask, 64);
    const float lg = m + __logf(l);

    if (sub == 0) {
        float4 o0, o1;
        o0.x = v[0] - lg; o0.y = v[1] - lg; o0.z = v[2] - lg; o0.w = v[3] - lg;
        o1.x = v[4] - lg; o1.y = v[5] - lg; o1.z = v[6] - lg; o1.w = v[7] - lg;
        *(float4*)&out[node * N_CLASSES + o8]     = o0;
        *(float4*)&out[node * N_CLASSES + o8 + 4] = o1;
    }
}

// ---------------------------------------------------------------------------
// Launch
// ---------------------------------------------------------------------------
extern "C" void kernel_launch(void* const* d_in, const int* in_sizes, int n_in,
                              void* d_out, int out_size, void* d_ws, size_t ws_size,
                              hipStream_t stream) {
    const float* x    = (const float*)d_in[0];
    const int*   edge = (const int*)d_in[1];   // [2,E]: src then dst
    const float* W    = (const float*)d_in[2];
    const float* b    = (const float*)d_in[3];
    float* out = (float*)d_out;

    char* ws = (char*)d_ws;
    int*    meta   = (int*)(ws);
    int*    bcnt   = (int*)(ws + OFF_BCNT);
    int*    binned = (int*)(ws + OFF_BINNED);
    __half* zp     = (__half*)(ws + OFF_ZP);

    const int* srcv = edge;
    const int* dstv = edge + N_EDGES;

    init_kernel<<<(NB + 255) / 256, 256, 0, stream>>>(bcnt);
    bin_kernel<<<NBLK_A, 1024, 0, stream>>>(srcv, dstv, bcnt, binned);
    sortdeg_kernel<<<NB, 512, 0, stream>>>(bcnt, binned, meta);
    gemm_kernel<<<NBLK_G, 256, 0, stream>>>(x, W, meta, zp);
    agg_kernel<<<N_NODES / 4, 256, 0, stream>>>(meta, binned, zp, b, out);
}

// Round 11
// 188.194 us; speedup vs baseline: 5.1193x; 1.0057x over previous
//
#include <hip/hip_runtime.h>
#include <hip/hip_bf16.h>
#include <hip/hip_fp16.h>
#include <math.h>

#define N_NODES   100000
#define N_EDGES   1600000
#define D_FEAT    128
#define N_CLASSES 64

#define BKT_SHIFT 7                     // 128 nodes per bucket
#define BKT_NODES 128
#define NB        782                   // ceil(100000/128)
#define CAP       2560                  // per-bucket capacity (avg 2048)
#define CHUNK     8192                  // edges per bin block
#define NBLK_A    ((N_EDGES + CHUNK - 1) / CHUNK)   // 196
#define NBLK_G    ((N_NODES + 63) / 64)             // 1563

// ws layout (max extent 21,212,160 B — well under proven 34 MB):
//   meta   @ 0          (400,000 B)  start|(indeg<<21)
//   bcnt   @ 400,384    (3,128 B)
//   binned @ 404,480    (8,007,680 B)
//   zp     @ 8,412,160  (12,800,000 B, fp16)
#define OFF_BCNT   400384
#define OFF_BINNED 404480
#define OFF_ZP     8412160

typedef __attribute__((ext_vector_type(8))) short bf16x8;
typedef __attribute__((ext_vector_type(4))) float f32x4;
typedef __attribute__((ext_vector_type(4))) unsigned int u32x4;

static __device__ inline unsigned f2bf1(float f) {
    unsigned u = __float_as_uint(f);
    return (u + 0x7FFF + ((u >> 16) & 1)) >> 16;     // RNE
}
static __device__ inline unsigned pack2(float a, float b) {
    return f2bf1(a) | (f2bf1(b) << 16);
}
static __device__ inline float2 h2f2(unsigned u) {
    __half2 h = *(__half2*)&u;
    return __half22float2(h);
}

// ---------------------------------------------------------------------------
// K1: bin edges into NB coarse buckets (contiguous per-block runs).
//     Single pass over dst: stage into LDS during histogram, scatter from LDS.
// ---------------------------------------------------------------------------
__global__ __launch_bounds__(1024) void bin_kernel(const int* __restrict__ src,
                                                   const int* __restrict__ dst,
                                                   int* __restrict__ bcnt,
                                                   int* __restrict__ binned) {
    __shared__ int hist[NB];
    __shared__ int rbase[NB];
    __shared__ int dbuf[CHUNK];                // 32 KB
    const int tid = threadIdx.x;
    const int e0 = blockIdx.x * CHUNK;
    const int e1 = min(e0 + CHUNK, N_EDGES);
    const int n  = e1 - e0;

    for (int i = tid; i < NB; i += 1024) hist[i] = 0;
    __syncthreads();

    for (int i = tid; i < n; i += 1024) {
        int d = dst[e0 + i];
        dbuf[i] = d;
        atomicAdd(&hist[d >> BKT_SHIFT], 1);
    }
    __syncthreads();

    for (int i = tid; i < NB; i += 1024) {
        int h = hist[i];
        if (h) rbase[i] = atomicAdd(&bcnt[i], h);
        hist[i] = 0;                           // reuse as within-run cursor
    }
    __syncthreads();

    for (int i = tid; i < n; i += 1024) {
        int d = dbuf[i];
        int s = src[e0 + i];
        int bkt = d >> BKT_SHIFT;
        int pos = atomicAdd(&hist[bkt], 1);
        int off = rbase[bkt] + pos;
        if (off < CAP)                         // memory guard
            binned[bkt * CAP + off] = (s << BKT_SHIFT) | (d & (BKT_NODES - 1));
    }
}

// ---------------------------------------------------------------------------
// K2: per-bucket in-place sort-by-node + degree metadata.
// ---------------------------------------------------------------------------
__global__ __launch_bounds__(1024) void sortdeg_kernel(const int* __restrict__ bcnt,
                                                       int* __restrict__ binned,
                                                       int* __restrict__ meta) {
    __shared__ int buf[CAP];
    __shared__ int hcnt[BKT_NODES];
    __shared__ int cur[BKT_NODES];
    __shared__ int rowstart[BKT_NODES + 1];

    const int tid  = threadIdx.x;
    const int lane = tid & 63;
    const int wid  = tid >> 6;

    if (tid < BKT_NODES) { hcnt[tid] = 0; cur[tid] = 0; }
    __syncthreads();

    const int n    = min(bcnt[blockIdx.x], CAP);
    const int base = blockIdx.x * CAP;

    for (int i = tid; i < n; i += 1024) {
        int v = binned[base + i];
        buf[i] = v;
        atomicAdd(&hcnt[v & (BKT_NODES - 1)], 1);
    }
    __syncthreads();

    if (wid == 0) {
        int v0 = hcnt[lane];
        int v1 = hcnt[64 + lane];
        int s0 = v0;
#pragma unroll
        for (int off = 1; off < 64; off <<= 1) {
            int t = __shfl_up(s0, off, 64);
            if (lane >= off) s0 += t;
        }
        int tot0 = __shfl(s0, 63, 64);
        int s1 = v1;
#pragma unroll
        for (int off = 1; off < 64; off <<= 1) {
            int t = __shfl_up(s1, off, 64);
            if (lane >= off) s1 += t;
        }
        s1 += tot0;
        if (lane == 0) rowstart[0] = 0;
        rowstart[1 + lane]  = s0;
        rowstart[65 + lane] = s1;
    }
    __syncthreads();

    for (int i = tid; i < n; i += 1024) {
        int v  = buf[i];
        int nd = v & (BKT_NODES - 1);
        int p  = atomicAdd(&cur[nd], 1);
        binned[base + rowstart[nd] + p] = v >> BKT_SHIFT;
    }

    if (tid < BKT_NODES) {
        int node = blockIdx.x * BKT_NODES + tid;
        if (node < N_NODES) {
            int st = base + rowstart[tid];
            int dg = min(hcnt[tid], 2047);
            meta[node] = st | (dg << 21);
        }
    }
}

// ---------------------------------------------------------------------------
// K3: zp[i][c] = rsqrt(indeg[i]+1) * (x @ W^T)[i][c]  via bf16 MFMA, fp16 out.
// ---------------------------------------------------------------------------
__global__ __launch_bounds__(256) void gemm_kernel(const float* __restrict__ x,
                                                   const float* __restrict__ W,
                                                   const int* __restrict__ meta,
                                                   __half* __restrict__ zp) {
    __shared__ short Xb[64 * 136];
    __shared__ short Wb[64 * 136];
    const int tid  = threadIdx.x;
    const int row0 = blockIdx.x * 64;

    const float4* __restrict__ W4 = (const float4*)W;
    for (int idx = tid; idx < 64 * 32; idx += 256) {
        int nn = idx >> 5, k4 = idx & 31;
        float4 v = W4[idx];
        uint2 p;
        p.x = pack2(v.x, v.y);
        p.y = pack2(v.z, v.w);
        *(uint2*)&Wb[nn * 136 + k4 * 4] = p;
    }
    const float4* __restrict__ x4 = (const float4*)x;
    for (int idx = tid; idx < 64 * 32; idx += 256) {
        int r = idx >> 5, k4 = idx & 31;
        int gr = min(row0 + r, N_NODES - 1);
        float4 v = x4[gr * 32 + k4];
        uint2 p;
        p.x = pack2(v.x, v.y);
        p.y = pack2(v.z, v.w);
        *(uint2*)&Xb[r * 136 + k4 * 4] = p;
    }
    __syncthreads();

    const int lane = tid & 63;
    const int wv   = tid >> 6;
    const int m    = lane & 15;
    const int half = lane >> 4;

    bf16x8 bfr[4][4];
#pragma unroll
    for (int t = 0; t < 4; t++)
#pragma unroll
        for (int j = 0; j < 4; j++)
            bfr[t][j] = *(bf16x8*)&Wb[(j * 16 + m) * 136 + t * 32 + half * 8];

    f32x4 acc[4];
#pragma unroll
    for (int j = 0; j < 4; j++) acc[j] = (f32x4){0.f, 0.f, 0.f, 0.f};

#pragma unroll
    for (int t = 0; t < 4; t++) {
        bf16x8 a = *(bf16x8*)&Xb[(wv * 16 + m) * 136 + t * 32 + half * 8];
#pragma unroll
        for (int j = 0; j < 4; j++)
            acc[j] = __builtin_amdgcn_mfma_f32_16x16x32_bf16(a, bfr[t][j], acc[j], 0, 0, 0);
    }

#pragma unroll
    for (int r = 0; r < 4; r++) {
        const int row = row0 + wv * 16 + half * 4 + r;
        if (row < N_NODES) {
            const int dg = ((unsigned)meta[row]) >> 21;
            const float dinv = rsqrtf((float)(dg + 1));
#pragma unroll
            for (int j = 0; j < 4; j++)
                zp[row * N_CLASSES + j * 16 + m] = __float2half(acc[j][r] * dinv);
        }
    }
}

// ---------------------------------------------------------------------------
// K4: gather-accumulate + fused epilogue. One wave per node.
//     Index block (64 idx) loaded ONCE per 64-edge batch; all zp gathers
//     within a batch are then independent (rows via shfl) -> high MLP.
//     lane = (sub = edge slot 0..7, o8 = 8-class chunk); 16 B/lane gathers.
// ---------------------------------------------------------------------------
__global__ __launch_bounds__(256) void agg_kernel(const int* __restrict__ meta,
                                                  const int* __restrict__ binned,
                                                  const __half* __restrict__ zp,
                                                  const float* __restrict__ b,
                                                  float* __restrict__ out) {
    const int node = blockIdx.x * 4 + (threadIdx.x >> 6);
    const int lane = threadIdx.x & 63;
    const int sub  = lane >> 3;                 // edge slot 0..7
    const int o8   = (lane & 7) * 8;            // class octet start

    const unsigned mv = (unsigned)meta[node];
    const int start = mv & 0x1FFFFF;
    const int cnt   = mv >> 21;

    float a[8] = {0.f, 0.f, 0.f, 0.f, 0.f, 0.f, 0.f, 0.f};
    for (int base = 0; base < cnt; base += 64) {
        const int bn = min(cnt - base, 64);
        // one load -> 64 indices for this batch
        const int sidx = binned[start + base + min(lane, bn - 1)];
        const int jm = (bn + 7) >> 3;
        for (int j = 0; j < jm; j++) {
            const int eid = j * 8 + sub;
            const int row = __shfl(sidx, min(eid, bn - 1), 64);
            const u32x4 g = *(const u32x4*)&zp[row * N_CLASSES + o8];
            if (eid < bn) {
#pragma unroll
                for (int k = 0; k < 4; k++) {
                    float2 f = h2f2(g[k]);
                    a[2 * k]     += f.x;
                    a[2 * k + 1] += f.y;
                }
            }
        }
    }
    // combine the 8 edge slots (xor 8,16,32): each octet-lane ends with full sums
#pragma unroll
    for (int mask = 8; mask <= 32; mask <<= 1)
#pragma unroll
        for (int k = 0; k < 8; k++)
            a[k] += __shfl_xor(a[k], mask, 64);

    // self-loop
    const u32x4 sg = *(const u32x4*)&zp[node * N_CLASSES + o8];
#pragma unroll
    for (int k = 0; k < 4; k++) {
        float2 f = h2f2(sg[k]);
        a[2 * k]     += f.x;
        a[2 * k + 1] += f.y;
    }

    const float dinv = rsqrtf((float)(cnt + 1));
    float v[8];
#pragma unroll
    for (int k = 0; k < 8; k++) v[k] = a[k] * dinv + b[o8 + k];

    // max/sum over 8 local + the 8 octet lanes (masks 1,2,4 stay in-octet)
    float m = v[0];
#pragma unroll
    for (int k = 1; k < 8; k++) m = fmaxf(m, v[k]);
#pragma unroll
    for (int mask = 1; mask <= 4; mask <<= 1)
        m = fmaxf(m, __shfl_xor(m, mask, 64));
    float l = 0.f;
#pragma unroll
    for (int k = 0; k < 8; k++) l += __expf(v[k] - m);
#pragma unroll
    for (int mask = 1; mask <= 4; mask <<= 1)
        l += __shfl_xor(l, mask, 64);
    const float lg = m + __logf(l);

    if (sub == 0) {
        float4 o0, o1;
        o0.x = v[0] - lg; o0.y = v[1] - lg; o0.z = v[2] - lg; o0.w = v[3] - lg;
        o1.x = v[4] - lg; o1.y = v[5] - lg; o1.z = v[6] - lg; o1.w = v[7] - lg;
        *(float4*)&out[node * N_CLASSES + o8]     = o0;
        *(float4*)&out[node * N_CLASSES + o8 + 4] = o1;
    }
}

// ---------------------------------------------------------------------------
// Launch
// ---------------------------------------------------------------------------
extern "C" void kernel_launch(void* const* d_in, const int* in_sizes, int n_in,
                              void* d_out, int out_size, void* d_ws, size_t ws_size,
                              hipStream_t stream) {
    const float* x    = (const float*)d_in[0];
    const int*   edge = (const int*)d_in[1];   // [2,E]: src then dst
    const float* W    = (const float*)d_in[2];
    const float* b    = (const float*)d_in[3];
    float* out = (float*)d_out;

    char* ws = (char*)d_ws;
    int*    meta   = (int*)(ws);
    int*    bcnt   = (int*)(ws + OFF_BCNT);
    int*    binned = (int*)(ws + OFF_BINNED);
    __half* zp     = (__half*)(ws + OFF_ZP);

    const int* srcv = edge;
    const int* dstv = edge + N_EDGES;

    hipMemsetAsync(bcnt, 0, NB * sizeof(int), stream);
    bin_kernel<<<NBLK_A, 1024, 0, stream>>>(srcv, dstv, bcnt, binned);
    sortdeg_kernel<<<NB, 1024, 0, stream>>>(bcnt, binned, meta);
    gemm_kernel<<<NBLK_G, 256, 0, stream>>>(x, W, meta, zp);
    agg_kernel<<<N_NODES / 4, 256, 0, stream>>>(meta, binned, zp, b, out);
}